// Round 13
// baseline (408.673 us; speedup 1.0000x reference)
//
#include <hip/hip_runtime.h>
#include <math.h>

#define H2 128

typedef unsigned short ushort_t;
typedef unsigned int uint_t;
typedef __attribute__((ext_vector_type(8))) short bf16x8;
typedef __attribute__((ext_vector_type(4))) float f32x4;
typedef __attribute__((ext_vector_type(2))) float f32x2;

static __device__ inline ushort_t bf16_1(float f) {
  uint_t u = __float_as_uint(f);
  u += 0x7fffu + ((u >> 16) & 1u);
  return (ushort_t)(u >> 16);
}
static __device__ inline float bf_up(ushort_t s) { return __uint_as_float((uint_t)s << 16); }
static __device__ inline float bf_lo(uint_t u) { return __uint_as_float(u << 16); }
static __device__ inline float bf_hi(uint_t u) { return __uint_as_float(u & 0xffff0000u); }

// ---------------- init: zero deg/pool/total + W2 -> bf16 transposed [n][k] ----------------
__global__ __launch_bounds__(256) void k_init(const float* __restrict__ W2, ushort_t* __restrict__ w2bt,
                                              int* __restrict__ deg, float* __restrict__ pool,
                                              int* __restrict__ total, int N) {
  int idx = blockIdx.x * 256 + threadIdx.x;
  if (idx < 32768) {
    int n = idx >> 8, k = idx & 255;
    w2bt[idx] = bf16_1(W2[(size_t)k * 128 + n]);
  }
  if (idx < N) deg[idx] = 0;
  if (idx < H2) pool[idx] = 0.f;
  if (idx == 0) *total = 0;
}

// ---------------- in-degree histogram + per-edge rank (scalar: max TLP for atomic returns) ----------------
__global__ __launch_bounds__(256) void k_degree(const int* __restrict__ col, int* __restrict__ deg,
                                                int* __restrict__ rank, int E) {
  int e = blockIdx.x * 256 + threadIdx.x;
  if (e < E) rank[e] = atomicAdd(&deg[col[e]], 1);   // rank in [0, indeg)
}

// ---------------- dis, xs8 (bf16x4-packed dis*x), col_off, packed meta (off,cnt,dis) ----------------
__global__ __launch_bounds__(256) void k_offs(const int* __restrict__ deg, const float* __restrict__ x,
                                              float* __restrict__ dis, uint2* __restrict__ xs8,
                                              int* __restrict__ col_off, int4* __restrict__ metas,
                                              int* __restrict__ total, int N) {
  int i = blockIdx.x * 256 + threadIdx.x;
  int lane = threadIdx.x & 63;
  int v = (i < N) ? deg[i] : 0;          // in-edge count (self-loop excluded)
  float di = rsqrtf((float)(v + 1));
  if (i < N) {
    dis[i] = di;
    float4 xv = ((const float4*)x)[i];
    uint2 pk;
    pk.x = (uint_t)bf16_1(di * xv.x) | ((uint_t)bf16_1(di * xv.y) << 16);
    pk.y = (uint_t)bf16_1(di * xv.z) | ((uint_t)bf16_1(di * xv.w) << 16);
    xs8[i] = pk;
  }
  int pref = v;
#pragma unroll
  for (int s = 1; s < 64; s <<= 1) {
    int t = __shfl_up(pref, s, 64);
    if (lane >= s) pref += t;
  }
  int wavesum = __shfl(pref, 63, 64);
  int base = 0;
  if (lane == 63) base = atomicAdd(total, wavesum);
  base = __shfl(base, 63, 64);
  if (i < N) {
    int off = base + pref - v;
    col_off[i] = off;
    metas[i] = make_int4(off, v, (int)__float_as_uint(di), 0);
  }
}

// ---------------- scatter edges into CSR (atomic-free via rank), scalar + pad ----------------
__global__ __launch_bounds__(256) void k_scatter(const int* __restrict__ row, const int* __restrict__ col,
                                                 const int* __restrict__ col_off, const int* __restrict__ rank,
                                                 int* __restrict__ csr_src, int E) {
  int e = blockIdx.x * 256 + threadIdx.x;
  if (e < E) {
    int c = col[e];
    csr_src[col_off[c] + rank[e]] = row[e];
  }
  if (blockIdx.x == 0 && threadIdx.x < 64) csr_src[E + threadIdx.x] = 0;  // safe overrun pad
}

// ---------------- layer-1 aggregation: thread-per-node masked 8-burst ----------------
__global__ __launch_bounds__(256) void k_l1gather(const uint2* __restrict__ xs8, const int* __restrict__ csr_src,
                                                  const int4* __restrict__ metas, float* __restrict__ aggx, int N) {
  int c = blockIdx.x * 256 + threadIdx.x;
  if (c >= N) return;
  int4 m = metas[c];
  int base = m.x, cnt = m.y;
  float dc = __uint_as_float((uint_t)m.z);
  uint2 s = xs8[c];
  float a0 = bf_lo(s.x), a1 = bf_hi(s.x), a2 = bf_lo(s.y), a3 = bf_hi(s.y);
  for (int j = 0; j < cnt; j += 8) {
    int idx[8];
#pragma unroll
    for (int q = 0; q < 8; ++q) idx[q] = csr_src[base + j + q];   // overrun ≤8 -> next seg / pad
    uint2 v[8];
#pragma unroll
    for (int q = 0; q < 8; ++q) v[q] = xs8[idx[q]];
#pragma unroll
    for (int q = 0; q < 8; ++q) {
      uint2 w = (j + q < cnt) ? v[q] : make_uint2(0u, 0u);
      a0 += bf_lo(w.x); a1 += bf_hi(w.x);
      a2 += bf_lo(w.y); a3 += bf_hi(w.y);
    }
  }
  ((float4*)aggx)[c] = make_float4(dc * a0, dc * a1, dc * a2, dc * a3);
}

// ---------------- fused MFMA gemm: h1 = relu(aggx@W1+b1); t2f8 = fp8(dis*(h1@W2)) ----------------
// Epilogue stores SLAB layout: slab s (dims 16s..16s+15) at t2f8[(s*N + node)*16B].
__global__ __launch_bounds__(256) void k_gemm(const float* __restrict__ aggx, const float* __restrict__ W1,
                                              const float* __restrict__ b1, const ushort_t* __restrict__ w2bt,
                                              const float* __restrict__ dis, uint_t* __restrict__ t2f8, int N) {
  __shared__ ushort_t h1s[64 * 264];   // [node][k] pad 256->264; reused as epilogue tile [64][132]
  __shared__ float axs[64][4];
  __shared__ float w1s[1024];
  __shared__ float b1s[256];
  int tid = threadIdx.x;
  int node0 = blockIdx.x * 64;
  {
    int n = tid >> 2, k = tid & 3;
    int node = node0 + n;
    axs[n][k] = (node < N) ? aggx[node * 4 + k] : 0.f;
#pragma unroll
    for (int q = 0; q < 4; ++q) w1s[tid + 256 * q] = W1[tid + 256 * q];
    b1s[tid] = b1[tid];
  }
  __syncthreads();
  {
    int n = tid >> 2;
    float a0 = axs[n][0], a1 = axs[n][1], a2 = axs[n][2], a3 = axs[n][3];
    int cp0 = (tid & 3) * 32;
    uint_t* h1w = (uint_t*)h1s;
#pragma unroll 4
    for (int q = 0; q < 32; ++q) {
      int cp = cp0 + q, c = cp * 2;
      float v0 = b1s[c], v1 = b1s[c + 1];
      v0 = fmaf(a0, w1s[c], v0);         v1 = fmaf(a0, w1s[c + 1], v1);
      v0 = fmaf(a1, w1s[256 + c], v0);   v1 = fmaf(a1, w1s[256 + c + 1], v1);
      v0 = fmaf(a2, w1s[512 + c], v0);   v1 = fmaf(a2, w1s[512 + c + 1], v1);
      v0 = fmaf(a3, w1s[768 + c], v0);   v1 = fmaf(a3, w1s[768 + c + 1], v1);
      v0 = fmaxf(v0, 0.f); v1 = fmaxf(v1, 0.f);
      h1w[n * 132 + cp] = (uint_t)bf16_1(v0) | ((uint_t)bf16_1(v1) << 16);
    }
  }
  __syncthreads();
  int wv = tid >> 6, lane = tid & 63;
  int quad = lane >> 4, sel = lane & 15;
  f32x4 acc[4][2];
#pragma unroll
  for (int m = 0; m < 4; ++m)
#pragma unroll
    for (int i = 0; i < 2; ++i) acc[m][i] = (f32x4){0.f, 0.f, 0.f, 0.f};
  const ushort_t* bp0 = w2bt + (size_t)(wv * 32 + sel) * 256 + quad * 8;
  const ushort_t* bp1 = bp0 + 16 * 256;
#pragma unroll
  for (int k0 = 0; k0 < 256; k0 += 32) {
    bf16x8 bf0 = *(const bf16x8*)(bp0 + k0);
    bf16x8 bf1 = *(const bf16x8*)(bp1 + k0);
#pragma unroll
    for (int m = 0; m < 4; ++m) {
      bf16x8 af = *(const bf16x8*)&h1s[(m * 16 + sel) * 264 + k0 + quad * 8];
      acc[m][0] = __builtin_amdgcn_mfma_f32_16x16x32_bf16(af, bf0, acc[m][0], 0, 0, 0);
      acc[m][1] = __builtin_amdgcn_mfma_f32_16x16x32_bf16(af, bf1, acc[m][1], 0, 0, 0);
    }
  }
  __syncthreads();
  ushort_t* tile = h1s;   // reuse as [64][132]
#pragma unroll
  for (int m = 0; m < 4; ++m) {
#pragma unroll
    for (int r = 0; r < 4; ++r) {
      int rl = m * 16 + quad * 4 + r;
      int node = node0 + rl;
      float dn = (node < N) ? dis[node] : 0.f;
      tile[rl * 132 + wv * 32 + sel]      = bf16_1(dn * acc[m][0][r]);
      tile[rl * 132 + wv * 32 + 16 + sel] = bf16_1(dn * acc[m][1][r]);
    }
  }
  __syncthreads();
  // slab-layout store: q = slab, 256 threads cover 64 nodes x 4 dwords contiguous (1KB/slab)
#pragma unroll
  for (int q = 0; q < 8; ++q) {
    int nl = tid >> 2, w = tid & 3;
    int node = node0 + nl;
    if (node < N) {
      const ushort_t* src = &tile[nl * 132 + q * 16 + w * 4];
      float f0 = bf_up(src[0]), f1 = bf_up(src[1]), f2 = bf_up(src[2]), f3 = bf_up(src[3]);
      int wrd = __builtin_amdgcn_cvt_pk_fp8_f32(f0, f1, 0, false);
      wrd = __builtin_amdgcn_cvt_pk_fp8_f32(f2, f3, wrd, true);
      t2f8[((size_t)q * N + node) * 4 + w] = (uint_t)wrd;
    }
  }
}

// ---------------- layer-2 aggregation: per-XCD column slabs ----------------
// slab = blockIdx&7 (1.6MB slice -> pinned to one XCD's L2 by round-robin dispatch).
// Wave = 16 edge-groups x 4 lanes; one vector load covers 16 edges' 16B slices.
// Node pipeline: next node's meta+indices prefetched during current node's drain.
__global__ __launch_bounds__(256) void k_agg2(const int* __restrict__ csr_src, const int4* __restrict__ metas,
                                              const unsigned char* __restrict__ t2f8, const float* __restrict__ b2,
                                              float* __restrict__ pool, int N) {
  int wave = threadIdx.x >> 6;
  int lane = threadIdx.x & 63;
  int eg = lane >> 2;        // edge group 0..15
  int cls = lane & 3;        // dword within 16B slice
  int slab = blockIdx.x & 7;
  const unsigned char* sb = t2f8 + (size_t)slab * N * 16;
  int gw = (blockIdx.x >> 3) * 4 + wave;
  int nw = (gridDim.x >> 3) * 4;
  float4 bb = *(const float4*)&b2[slab * 16 + cls * 4];
  float p0 = 0.f, p1 = 0.f, p2 = 0.f, p3 = 0.f;
  int c = gw;
  if (c < N) {
    int4 m = metas[c];
    int base = __builtin_amdgcn_readfirstlane(m.x);
    int cnt  = __builtin_amdgcn_readfirstlane(m.y);
    float dc = __uint_as_float((uint_t)__builtin_amdgcn_readfirstlane(m.z));
    int idxv = csr_src[base + eg];                 // round-0 indices (prefetched)
    while (true) {
      f32x2 a01 = {0.f, 0.f}, a23 = {0.f, 0.f};
      for (int j = 0; j < cnt; j += 16) {
        uint_t u = *(const uint_t*)(sb + ((size_t)(uint_t)idxv << 4) + (cls << 2));
        int nj = j + 16;
        int idxn = 0;
        if (nj < cnt) idxn = csr_src[base + nj + eg];   // issued before u's waitcnt
        uint_t v = (j + eg < cnt) ? u : 0u;
        a01 += __builtin_amdgcn_cvt_pk_f32_fp8(v, false);
        a23 += __builtin_amdgcn_cvt_pk_f32_fp8(v, true);
        idxv = idxn;
      }
      // butterfly reduce across 16 edge groups (xor 4,8,16,32)
#pragma unroll
      for (int s = 4; s < 64; s <<= 1) {
        a01.x += __shfl_xor(a01.x, s, 64);
        a01.y += __shfl_xor(a01.y, s, 64);
        a23.x += __shfl_xor(a23.x, s, 64);
        a23.y += __shfl_xor(a23.y, s, 64);
      }
      // prefetch next node during epilogue
      int cn = c + nw;
      int baseN = 0, cntN = 0, idxN = 0;
      float dcN = 0.f;
      if (cn < N) {
        int4 mn = metas[cn];
        baseN = __builtin_amdgcn_readfirstlane(mn.x);
        cntN  = __builtin_amdgcn_readfirstlane(mn.y);
        dcN = __uint_as_float((uint_t)__builtin_amdgcn_readfirstlane(mn.z));
        idxN = csr_src[baseN + eg];
      }
      // self term + relu + pool
      uint_t us = *(const uint_t*)(sb + ((size_t)(uint_t)c << 4) + (cls << 2));
      a01 += __builtin_amdgcn_cvt_pk_f32_fp8(us, false);
      a23 += __builtin_amdgcn_cvt_pk_f32_fp8(us, true);
      p0 += fmaxf(fmaf(dc, a01.x, bb.x), 0.f);
      p1 += fmaxf(fmaf(dc, a01.y, bb.y), 0.f);
      p2 += fmaxf(fmaf(dc, a23.x, bb.z), 0.f);
      p3 += fmaxf(fmaf(dc, a23.y, bb.w), 0.f);
      if (cn >= N) break;
      c = cn; base = baseN; cnt = cntN; dc = dcN; idxv = idxN;
    }
  }
  __shared__ float red[4][4][4];   // [wave][class][k]
  if (lane < 4) {
    red[wave][lane][0] = p0; red[wave][lane][1] = p1;
    red[wave][lane][2] = p2; red[wave][lane][3] = p3;
  }
  __syncthreads();
  if (threadIdx.x < 16) {
    int cl = threadIdx.x >> 2, k = threadIdx.x & 3;
    float s = red[0][cl][k] + red[1][cl][k] + red[2][cl][k] + red[3][cl][k];
    atomicAdd(&pool[slab * 16 + cl * 4 + k], s);
  }
}

// ---------------- final ----------------
__global__ __launch_bounds__(128) void k_final(const float* __restrict__ pool, const float* __restrict__ Wl,
                                               const float* __restrict__ bl, float* __restrict__ out, float invN) {
  __shared__ float red[128];
  int t = threadIdx.x;
  red[t] = pool[t] * invN * Wl[t];
  __syncthreads();
  for (int s = 64; s > 0; s >>= 1) {
    if (t < s) red[t] += red[t + s];
    __syncthreads();
  }
  if (t == 0) out[0] = 1.f / (1.f + expf(-(red[0] + bl[0])));
}

extern "C" void kernel_launch(void* const* d_in, const int* in_sizes, int n_in,
                              void* d_out, int out_size, void* d_ws, size_t ws_size,
                              hipStream_t stream) {
  const float* x  = (const float*)d_in[0];
  const int*   ei = (const int*)d_in[1];
  const float* W1 = (const float*)d_in[2];
  const float* b1 = (const float*)d_in[3];
  const float* W2 = (const float*)d_in[4];
  const float* b2 = (const float*)d_in[5];
  const float* Wl = (const float*)d_in[6];
  const float* bl = (const float*)d_in[7];
  int N = in_sizes[0] / 4;
  int E = in_sizes[1] / 2;
  const int* row = ei;
  const int* col = ei + E;

  char* w = (char*)d_ws;
  size_t off = 0;
  auto alloc = [&](size_t bytes) {
    void* p = w + off;
    off += (bytes + 255) & ~(size_t)255;
    return p;
  };
  int*      deg     = (int*)alloc((size_t)N * 4);
  float*    dis     = (float*)alloc((size_t)N * 4);
  int*      col_off = (int*)alloc((size_t)N * 4);
  int4*     metas   = (int4*)alloc((size_t)N * 16);
  int*      rank    = (int*)alloc((size_t)E * 4);
  int*      csr_src = (int*)alloc((size_t)(E + 64) * 4);
  uint2*    xs8     = (uint2*)alloc((size_t)N * 8);
  float*    aggx    = (float*)alloc((size_t)N * 16);
  ushort_t* w2bt    = (ushort_t*)alloc((size_t)128 * 256 * 2);
  uint_t*   t2f8    = (uint_t*)alloc((size_t)N * H2);
  float*    pool    = (float*)alloc(H2 * 4);
  int*      total   = (int*)alloc(4);
  (void)ws_size; (void)n_in; (void)out_size;

  int gN = (N + 255) / 256;
  int gE = (E + 255) / 256;

  k_init<<<gN, 256, 0, stream>>>(W2, w2bt, deg, pool, total, N);
  k_degree<<<gE, 256, 0, stream>>>(col, deg, rank, E);
  k_offs<<<gN, 256, 0, stream>>>(deg, x, dis, xs8, col_off, metas, total, N);
  k_scatter<<<gE, 256, 0, stream>>>(row, col, col_off, rank, csr_src, E);
  k_l1gather<<<gN, 256, 0, stream>>>(xs8, csr_src, metas, aggx, N);
  k_gemm<<<(N + 63) / 64, 256, 0, stream>>>(aggx, W1, b1, w2bt, dis, t2f8, N);
  k_agg2<<<2048, 256, 0, stream>>>(csr_src, metas, (const unsigned char*)t2f8, b2, pool, N);
  k_final<<<1, 128, 0, stream>>>(pool, Wl, bl, (float*)d_out, 1.0f / (float)N);
}

// Round 14
// 298.223 us; speedup vs baseline: 1.3704x; 1.3704x over previous
//
#include <hip/hip_runtime.h>
#include <math.h>

#define H2 128

typedef unsigned short ushort_t;
typedef unsigned int uint_t;
typedef __attribute__((ext_vector_type(8))) short bf16x8;
typedef __attribute__((ext_vector_type(4))) float f32x4;
typedef __attribute__((ext_vector_type(2))) float f32x2;

static __device__ inline ushort_t bf16_1(float f) {
  uint_t u = __float_as_uint(f);
  u += 0x7fffu + ((u >> 16) & 1u);
  return (ushort_t)(u >> 16);
}
static __device__ inline float bf_up(ushort_t s) { return __uint_as_float((uint_t)s << 16); }
static __device__ inline float bf_lo(uint_t u) { return __uint_as_float(u << 16); }
static __device__ inline float bf_hi(uint_t u) { return __uint_as_float(u & 0xffff0000u); }

// ---------------- init: zero deg/pool/total + W2 -> bf16 transposed [n][k] ----------------
__global__ __launch_bounds__(256) void k_init(const float* __restrict__ W2, ushort_t* __restrict__ w2bt,
                                              int* __restrict__ deg, float* __restrict__ pool,
                                              int* __restrict__ total, int N) {
  int idx = blockIdx.x * 256 + threadIdx.x;
  if (idx < 32768) {
    int n = idx >> 8, k = idx & 255;
    w2bt[idx] = bf16_1(W2[(size_t)k * 128 + n]);
  }
  if (idx < N) deg[idx] = 0;
  if (idx < H2) pool[idx] = 0.f;
  if (idx == 0) *total = 0;
}

// ---------------- in-degree histogram + per-edge rank (scalar: max TLP) ----------------
__global__ __launch_bounds__(256) void k_degree(const int* __restrict__ col, int* __restrict__ deg,
                                                int* __restrict__ rank, int E) {
  int e = blockIdx.x * 256 + threadIdx.x;
  if (e < E) rank[e] = atomicAdd(&deg[col[e]], 1);   // rank in [0, indeg)
}

// ---------------- dis, xs8 (bf16x4-packed dis*x), col_off, packed meta (off,cnt,dis) ----------------
__global__ __launch_bounds__(256) void k_offs(const int* __restrict__ deg, const float* __restrict__ x,
                                              float* __restrict__ dis, uint2* __restrict__ xs8,
                                              int* __restrict__ col_off, int4* __restrict__ metas,
                                              int* __restrict__ total, int N) {
  int i = blockIdx.x * 256 + threadIdx.x;
  int lane = threadIdx.x & 63;
  int v = (i < N) ? deg[i] : 0;          // in-edge count (self-loop excluded)
  float di = rsqrtf((float)(v + 1));
  if (i < N) {
    dis[i] = di;
    float4 xv = ((const float4*)x)[i];
    uint2 pk;
    pk.x = (uint_t)bf16_1(di * xv.x) | ((uint_t)bf16_1(di * xv.y) << 16);
    pk.y = (uint_t)bf16_1(di * xv.z) | ((uint_t)bf16_1(di * xv.w) << 16);
    xs8[i] = pk;
  }
  int pref = v;
#pragma unroll
  for (int s = 1; s < 64; s <<= 1) {
    int t = __shfl_up(pref, s, 64);
    if (lane >= s) pref += t;
  }
  int wavesum = __shfl(pref, 63, 64);
  int base = 0;
  if (lane == 63) base = atomicAdd(total, wavesum);
  base = __shfl(base, 63, 64);
  if (i < N) {
    int off = base + pref - v;
    col_off[i] = off;
    metas[i] = make_int4(off, v, (int)__float_as_uint(di), 0);
  }
}

// ---------------- scatter edges into CSR (atomic-free via rank), scalar + pad ----------------
__global__ __launch_bounds__(256) void k_scatter(const int* __restrict__ row, const int* __restrict__ col,
                                                 const int* __restrict__ col_off, const int* __restrict__ rank,
                                                 int* __restrict__ csr_src, int E) {
  int e = blockIdx.x * 256 + threadIdx.x;
  if (e < E) {
    int c = col[e];
    csr_src[col_off[c] + rank[e]] = row[e];
  }
  if (blockIdx.x == 0 && threadIdx.x < 64) csr_src[E + threadIdx.x] = 0;  // safe overrun pad
}

// ---------------- layer-1 aggregation: thread-per-node masked 8-burst (R11 form) ----------------
__global__ __launch_bounds__(256) void k_l1gather(const uint2* __restrict__ xs8, const int* __restrict__ csr_src,
                                                  const int4* __restrict__ metas, float* __restrict__ aggx, int N) {
  int c = blockIdx.x * 256 + threadIdx.x;
  if (c >= N) return;
  int4 m = metas[c];
  int base = m.x, cnt = m.y;
  float dc = __uint_as_float((uint_t)m.z);
  uint2 s = xs8[c];
  float a0 = bf_lo(s.x), a1 = bf_hi(s.x), a2 = bf_lo(s.y), a3 = bf_hi(s.y);
  for (int j = 0; j < cnt; j += 8) {
    int idx[8];
#pragma unroll
    for (int q = 0; q < 8; ++q) idx[q] = csr_src[base + j + q];   // overrun ≤8 -> next seg / pad
    uint2 v[8];
#pragma unroll
    for (int q = 0; q < 8; ++q) v[q] = xs8[idx[q]];
#pragma unroll
    for (int q = 0; q < 8; ++q) {
      uint2 w = (j + q < cnt) ? v[q] : make_uint2(0u, 0u);
      a0 += bf_lo(w.x); a1 += bf_hi(w.x);
      a2 += bf_lo(w.y); a3 += bf_hi(w.y);
    }
  }
  ((float4*)aggx)[c] = make_float4(dc * a0, dc * a1, dc * a2, dc * a3);
}

// ---------------- fused MFMA gemm: h1 = relu(aggx@W1+b1); t2f8 = fp8(dis*(h1@W2)) ----------------
// Epilogue stores 4-SLAB layout: slab s (dims 32s..32s+31) at t2f8[((s*N + node)*8 + w] dwords.
__global__ __launch_bounds__(256) void k_gemm(const float* __restrict__ aggx, const float* __restrict__ W1,
                                              const float* __restrict__ b1, const ushort_t* __restrict__ w2bt,
                                              const float* __restrict__ dis, uint_t* __restrict__ t2f8, int N) {
  __shared__ ushort_t h1s[64 * 264];   // [node][k] pad 256->264; reused as epilogue tile [64][132]
  __shared__ float axs[64][4];
  __shared__ float w1s[1024];
  __shared__ float b1s[256];
  int tid = threadIdx.x;
  int node0 = blockIdx.x * 64;
  {
    int n = tid >> 2, k = tid & 3;
    int node = node0 + n;
    axs[n][k] = (node < N) ? aggx[node * 4 + k] : 0.f;
#pragma unroll
    for (int q = 0; q < 4; ++q) w1s[tid + 256 * q] = W1[tid + 256 * q];
    b1s[tid] = b1[tid];
  }
  __syncthreads();
  {
    int n = tid >> 2;
    float a0 = axs[n][0], a1 = axs[n][1], a2 = axs[n][2], a3 = axs[n][3];
    int cp0 = (tid & 3) * 32;
    uint_t* h1w = (uint_t*)h1s;
#pragma unroll 4
    for (int q = 0; q < 32; ++q) {
      int cp = cp0 + q, c = cp * 2;
      float v0 = b1s[c], v1 = b1s[c + 1];
      v0 = fmaf(a0, w1s[c], v0);         v1 = fmaf(a0, w1s[c + 1], v1);
      v0 = fmaf(a1, w1s[256 + c], v0);   v1 = fmaf(a1, w1s[256 + c + 1], v1);
      v0 = fmaf(a2, w1s[512 + c], v0);   v1 = fmaf(a2, w1s[512 + c + 1], v1);
      v0 = fmaf(a3, w1s[768 + c], v0);   v1 = fmaf(a3, w1s[768 + c + 1], v1);
      v0 = fmaxf(v0, 0.f); v1 = fmaxf(v1, 0.f);
      h1w[n * 132 + cp] = (uint_t)bf16_1(v0) | ((uint_t)bf16_1(v1) << 16);
    }
  }
  __syncthreads();
  int wv = tid >> 6, lane = tid & 63;
  int quad = lane >> 4, sel = lane & 15;
  f32x4 acc[4][2];
#pragma unroll
  for (int m = 0; m < 4; ++m)
#pragma unroll
    for (int i = 0; i < 2; ++i) acc[m][i] = (f32x4){0.f, 0.f, 0.f, 0.f};
  const ushort_t* bp0 = w2bt + (size_t)(wv * 32 + sel) * 256 + quad * 8;
  const ushort_t* bp1 = bp0 + 16 * 256;
#pragma unroll
  for (int k0 = 0; k0 < 256; k0 += 32) {
    bf16x8 bf0 = *(const bf16x8*)(bp0 + k0);
    bf16x8 bf1 = *(const bf16x8*)(bp1 + k0);
#pragma unroll
    for (int m = 0; m < 4; ++m) {
      bf16x8 af = *(const bf16x8*)&h1s[(m * 16 + sel) * 264 + k0 + quad * 8];
      acc[m][0] = __builtin_amdgcn_mfma_f32_16x16x32_bf16(af, bf0, acc[m][0], 0, 0, 0);
      acc[m][1] = __builtin_amdgcn_mfma_f32_16x16x32_bf16(af, bf1, acc[m][1], 0, 0, 0);
    }
  }
  __syncthreads();
  ushort_t* tile = h1s;   // reuse as [64][132]
#pragma unroll
  for (int m = 0; m < 4; ++m) {
#pragma unroll
    for (int r = 0; r < 4; ++r) {
      int rl = m * 16 + quad * 4 + r;
      int node = node0 + rl;
      float dn = (node < N) ? dis[node] : 0.f;
      tile[rl * 132 + wv * 32 + sel]      = bf16_1(dn * acc[m][0][r]);
      tile[rl * 132 + wv * 32 + 16 + sel] = bf16_1(dn * acc[m][1][r]);
    }
  }
  __syncthreads();
  // 4-slab store: idx covers (node, slab*8+w); slab runs are 32B contiguous
#pragma unroll
  for (int q = 0; q < 8; ++q) {
    int idx = tid + 256 * q;
    int nl = idx >> 5, sw = idx & 31;
    int s = sw >> 3, w = sw & 7;
    int node = node0 + nl;
    if (node < N) {
      const ushort_t* src = &tile[nl * 132 + s * 32 + w * 4];
      float f0 = bf_up(src[0]), f1 = bf_up(src[1]), f2 = bf_up(src[2]), f3 = bf_up(src[3]);
      int wrd = __builtin_amdgcn_cvt_pk_fp8_f32(f0, f1, 0, false);
      wrd = __builtin_amdgcn_cvt_pk_fp8_f32(f2, f3, wrd, true);
      t2f8[((size_t)s * N + node) * 8 + w] = (uint_t)wrd;
    }
  }
}

// ---------------- layer-2 aggregation: 4-slab XCD-local, 8 nodes/wave, dims-in-lanes ----------------
// slab = blk&3 (3.2MB -> one XCD's L2 via blk%8 round-robin; slab s on XCDs {s,s+4}).
// Wave = 8 nodes (ns) x 8 lanes (dl); lane holds dims 32*slab+4*dl.. (one fp8 dword).
// Per round: 2 per-lane int4 index loads + 8 t2 loads = 64 L2-local lines in flight.
// No butterfly (dims stay in lanes), no readfirstlane selects (vector meta/idx loads).
__global__ __launch_bounds__(256) void k_agg2(const int* __restrict__ csr_src, const int4* __restrict__ metas,
                                              const unsigned char* __restrict__ t2f8, const float* __restrict__ b2,
                                              float* __restrict__ pool, int N) {
  int wave = threadIdx.x >> 6;
  int lane = threadIdx.x & 63;
  int ns = lane >> 3, dl = lane & 7;
  int slab = blockIdx.x & 3;
  const unsigned char* sb = t2f8 + (size_t)slab * N * 32;
  int gw = (blockIdx.x >> 2) * 4 + wave;
  int nw = (gridDim.x >> 2) * 4;
  int ngroups = (N + 7) >> 3;
  float4 bb = *(const float4*)&b2[slab * 32 + dl * 4];
  float p0 = 0.f, p1 = 0.f, p2 = 0.f, p3 = 0.f;
  for (int g = gw; g < ngroups; g += nw) {
    int c0 = g << 3;
    int cc = c0 + ns;
    float val = 1.f;
    if (cc >= N) { cc = N - 1; val = 0.f; }
    int4 m = metas[cc];                     // per-lane vector load (8 distinct 16B)
    int base = m.x, cnt = m.y;
    float dc = __uint_as_float((uint_t)m.z);
    int cmax = cnt;                          // max over the 8 nodes (ns = lane bits 3..5)
    cmax = max(cmax, __shfl_xor(cmax, 8, 64));
    cmax = max(cmax, __shfl_xor(cmax, 16, 64));
    cmax = max(cmax, __shfl_xor(cmax, 32, 64));
    uint_t us = *(const uint_t*)(sb + (size_t)(uint_t)cc * 32 + (dl << 2));
    f32x2 a01 = __builtin_amdgcn_cvt_pk_f32_fp8(us, false);   // self term
    f32x2 a23 = __builtin_amdgcn_cvt_pk_f32_fp8(us, true);
    for (int j = 0; j < cmax; j += 8) {
      int4 i0 = *(const int4*)(csr_src + base + j);       // 4 indices, per-lane
      int4 i1 = *(const int4*)(csr_src + base + j + 4);   // next 4 (overrun -> pad/next seg)
      uint_t u[8];
      u[0] = *(const uint_t*)(sb + (size_t)(uint_t)i0.x * 32 + (dl << 2));
      u[1] = *(const uint_t*)(sb + (size_t)(uint_t)i0.y * 32 + (dl << 2));
      u[2] = *(const uint_t*)(sb + (size_t)(uint_t)i0.z * 32 + (dl << 2));
      u[3] = *(const uint_t*)(sb + (size_t)(uint_t)i0.w * 32 + (dl << 2));
      u[4] = *(const uint_t*)(sb + (size_t)(uint_t)i1.x * 32 + (dl << 2));
      u[5] = *(const uint_t*)(sb + (size_t)(uint_t)i1.y * 32 + (dl << 2));
      u[6] = *(const uint_t*)(sb + (size_t)(uint_t)i1.z * 32 + (dl << 2));
      u[7] = *(const uint_t*)(sb + (size_t)(uint_t)i1.w * 32 + (dl << 2));
#pragma unroll
      for (int q = 0; q < 8; ++q) {
        uint_t v = (j + q < cnt) ? u[q] : 0u;
        a01 += __builtin_amdgcn_cvt_pk_f32_fp8(v, false);
        a23 += __builtin_amdgcn_cvt_pk_f32_fp8(v, true);
      }
    }
    p0 += val * fmaxf(fmaf(dc, a01.x, bb.x), 0.f);
    p1 += val * fmaxf(fmaf(dc, a01.y, bb.y), 0.f);
    p2 += val * fmaxf(fmaf(dc, a23.x, bb.z), 0.f);
    p3 += val * fmaxf(fmaf(dc, a23.y, bb.w), 0.f);
  }
  __shared__ float4 red[4][64];
  red[wave][lane] = make_float4(p0, p1, p2, p3);
  __syncthreads();
  if (threadIdx.x < 32) {
    int dl2 = threadIdx.x >> 2, k = threadIdx.x & 3;
    float s = 0.f;
#pragma unroll
    for (int w = 0; w < 4; ++w)
#pragma unroll
      for (int n2 = 0; n2 < 8; ++n2) {
        const float* rp = (const float*)&red[w][n2 * 8 + dl2];
        s += rp[k];
      }
    atomicAdd(&pool[slab * 32 + dl2 * 4 + k], s);
  }
}

// ---------------- final ----------------
__global__ __launch_bounds__(128) void k_final(const float* __restrict__ pool, const float* __restrict__ Wl,
                                               const float* __restrict__ bl, float* __restrict__ out, float invN) {
  __shared__ float red[128];
  int t = threadIdx.x;
  red[t] = pool[t] * invN * Wl[t];
  __syncthreads();
  for (int s = 64; s > 0; s >>= 1) {
    if (t < s) red[t] += red[t + s];
    __syncthreads();
  }
  if (t == 0) out[0] = 1.f / (1.f + expf(-(red[0] + bl[0])));
}

extern "C" void kernel_launch(void* const* d_in, const int* in_sizes, int n_in,
                              void* d_out, int out_size, void* d_ws, size_t ws_size,
                              hipStream_t stream) {
  const float* x  = (const float*)d_in[0];
  const int*   ei = (const int*)d_in[1];
  const float* W1 = (const float*)d_in[2];
  const float* b1 = (const float*)d_in[3];
  const float* W2 = (const float*)d_in[4];
  const float* b2 = (const float*)d_in[5];
  const float* Wl = (const float*)d_in[6];
  const float* bl = (const float*)d_in[7];
  int N = in_sizes[0] / 4;
  int E = in_sizes[1] / 2;
  const int* row = ei;
  const int* col = ei + E;

  char* w = (char*)d_ws;
  size_t off = 0;
  auto alloc = [&](size_t bytes) {
    void* p = w + off;
    off += (bytes + 255) & ~(size_t)255;
    return p;
  };
  int*      deg     = (int*)alloc((size_t)N * 4);
  float*    dis     = (float*)alloc((size_t)N * 4);
  int*      col_off = (int*)alloc((size_t)N * 4);
  int4*     metas   = (int4*)alloc((size_t)N * 16);
  int*      rank    = (int*)alloc((size_t)E * 4);
  int*      csr_src = (int*)alloc((size_t)(E + 64) * 4);
  uint2*    xs8     = (uint2*)alloc((size_t)N * 8);
  float*    aggx    = (float*)alloc((size_t)N * 16);
  ushort_t* w2bt    = (ushort_t*)alloc((size_t)128 * 256 * 2);
  uint_t*   t2f8    = (uint_t*)alloc((size_t)N * H2);
  float*    pool    = (float*)alloc(H2 * 4);
  int*      total   = (int*)alloc(4);
  (void)ws_size; (void)n_in; (void)out_size;

  int gN = (N + 255) / 256;
  int gE = (E + 255) / 256;

  k_init<<<gN, 256, 0, stream>>>(W2, w2bt, deg, pool, total, N);
  k_degree<<<gE, 256, 0, stream>>>(col, deg, rank, E);
  k_offs<<<gN, 256, 0, stream>>>(deg, x, dis, xs8, col_off, metas, total, N);
  k_scatter<<<gE, 256, 0, stream>>>(row, col, col_off, rank, csr_src, E);
  k_l1gather<<<gN, 256, 0, stream>>>(xs8, csr_src, metas, aggx, N);
  k_gemm<<<(N + 63) / 64, 256, 0, stream>>>(aggx, W1, b1, w2bt, dis, t2f8, N);
  k_agg2<<<2048, 256, 0, stream>>>(csr_src, metas, (const unsigned char*)t2f8, b2, pool, N);
  k_final<<<1, 128, 0, stream>>>(pool, Wl, bl, (float*)d_out, 1.0f / (float)N);
}